// Round 6
// baseline (1888.049 us; speedup 1.0000x reference)
//
#include <hip/hip_runtime.h>
#include <hip/hip_bf16.h>

#define T_STEPS 4

typedef __attribute__((ext_vector_type(8))) short short8v;   // 8 x bf16 bits
typedef __attribute__((ext_vector_type(4))) float f32x4;
typedef __attribute__((ext_vector_type(4))) unsigned short us4;

__device__ __forceinline__ float hsig(float x) {
    return fminf(fmaxf(0.2f * x + 0.5f, 0.f), 1.f);
}
__device__ __forceinline__ unsigned short f2bf(float v) {
    __hip_bfloat16 h = __float2bfloat16(v);   // RNE
    unsigned short u; __builtin_memcpy(&u, &h, 2); return u;
}

// pure helper: load one staged float4 (SSA value, never an array -> no scratch)
__device__ __forceinline__ float4 ldA(const float* __restrict__ src, int CsR, int ci0,
                                      int i, int y0, int x0, int H, int W)
{
    const int pix = i >> 3, c4 = (i & 7) << 2;
    const int hy = pix / 10, hx = pix - hy * 10;     // HS = 10
    const int iy = y0 + hy - 1, ix = x0 + hx - 1;
    float4 v = make_float4(0.f, 0.f, 0.f, 0.f);
    if (iy >= 0 && iy < H && ix >= 0 && ix < W) {
        const float* gp = src + ((size_t)iy * W + ix) * CsR + ci0 + c4;
        if (ci0 + c4 + 4 <= CsR) v = *(const float4*)gp;
        else {
            const int rem = CsR - ci0 - c4;
            if (rem > 0) { v.x = gp[0]; if (rem > 1) v.y = gp[1]; if (rem > 2) v.z = gp[2]; }
        }
    }
    return v;
}
__device__ __forceinline__ void stA(unsigned short* ldsA, float4 v, int i)
{
    const int pix = i >> 3, c4 = (i & 7) << 2;
    us4 hi;
    hi[0] = f2bf(v.x); hi[1] = f2bf(v.y); hi[2] = f2bf(v.z); hi[3] = f2bf(v.w);
    *(us4*)(ldsA + pix * 40 + c4) = hi;              // PITCH = 40
}

// ============ fused ConvLSTM timestep via bf16 MFMA implicit GEMM ============
// z[p, co'] = sum_{s,dd,ci} src_s[p+dd, ci] * W_s[dd, ci, co'];  co' = c*4+g.
// TILE=8 everywhere: staging = 4 NAMED float4 regs (s0..s3) -> no scratch
// (R5's lambda-captured stg[11] array was spilled: VGPR_Count=56 proved it).
// ISSUE(t+1) flies under tap-loop MFMAs; COMMIT after the barrier.
// B fragments straight from global, per-tap register double-buffer.
// Grid: (W/8, H/8, 4C/64); 256^2 layers -> 2048 blocks -> 4 blocks/CU TLP.
__global__ __launch_bounds__(256, 4)
void lstm_mfma(const float* __restrict__ xin, const float* __restrict__ hprev,
               float* __restrict__ cst, float* __restrict__ hout,
               const unsigned short* __restrict__ BtX,
               const unsigned short* __restrict__ BtH,
               const float* __restrict__ bias,
               int H, int W, int CiR, int CiP, int C)
{
    constexpr int HS = 10, PITCH = 40;
    extern __shared__ char smem[];
    unsigned short* ldsA = (unsigned short*)smem;    // [HS*HS][PITCH] ushorts

    const int tid = threadIdx.x, w = tid >> 6, lane = tid & 63;
    const int nb = blockIdx.z;
    const int y0 = blockIdx.y * 8, x0 = blockIdx.x * 8;
    const int NG = (4 * C) >> 4;
    const int kq = lane >> 4;
    const int abase = ((w >> 1) * 4 + ((lane >> 3) & 1)) * HS * PITCH
                    + (lane & 7) * PITCH + kq * 8;
    const int ngb = (w & 1) * 2;                     // this wave's n-group base

    f32x4 acc[2][2];
#pragma unroll
    for (int a = 0; a < 2; ++a)
#pragma unroll
        for (int b = 0; b < 2; ++b) acc[a][b] = (f32x4)0.f;

    const int nchx = CiP >> 5;
    const int nchh = hprev ? (C >> 5) : 0;           // t==0: conv(0,U)==0
    const int NCH = nchx + nchh;

    float4 s0, s1, s2, s3 = make_float4(0.f, 0.f, 0.f, 0.f);

#define AISSUE(tt) {                                                          \
        const int tci = (tt);                                                 \
        const float* __restrict__ srcp = (tci < nchx) ? xin : hprev;          \
        const int CsR_ = (tci < nchx) ? CiR : C;                              \
        const int ci0_ = ((tci < nchx) ? tci : tci - nchx) << 5;              \
        s0 = ldA(srcp, CsR_, ci0_, tid,       y0, x0, H, W);                  \
        s1 = ldA(srcp, CsR_, ci0_, tid + 256, y0, x0, H, W);                  \
        s2 = ldA(srcp, CsR_, ci0_, tid + 512, y0, x0, H, W);                  \
        if (tid < 32) s3 = ldA(srcp, CsR_, ci0_, tid + 768, y0, x0, H, W);    \
    }

    AISSUE(0)
    for (int t = 0; t < NCH; ++t) {
        const unsigned short* __restrict__ Bt = (t < nchx) ? BtX : BtH;
        const int bck = (t < nchx) ? t : t - nchx;
        __syncthreads();                             // prev MFMAs done w/ ldsA
        // ---- COMMIT staged regs -> LDS (cvt fp32->bf16) ----
        stA(ldsA, s0, tid); stA(ldsA, s1, tid + 256); stA(ldsA, s2, tid + 512);
        if (tid < 32) stA(ldsA, s3, tid + 768);
        __syncthreads();                             // tile visible
        // ---- prime B tap0; issue next chunk's A loads (fly w/ MFMAs) ----
        short8v bc0, bc1, bn0, bn1;
        {
            const size_t b0 = ((size_t)((bck * 9) * NG + nb * 4 + ngb) << 9) + lane * 8;
            bc0 = *(const short8v*)(Bt + b0);
            bc1 = *(const short8v*)(Bt + b0 + 512);
        }
        if (t + 1 < NCH) AISSUE(t + 1)
        // ---- 9 taps, register-pipelined B ----
#pragma unroll
        for (int dd = 0; dd < 9; ++dd) {
            if (dd < 8) {
                const size_t b1 = ((size_t)((bck * 9 + dd + 1) * NG + nb * 4 + ngb) << 9) + lane * 8;
                bn0 = *(const short8v*)(Bt + b1);
                bn1 = *(const short8v*)(Bt + b1 + 512);
            }
            const int dy = dd / 3, dx = dd % 3;
            short8v ah0 = *(const short8v*)(ldsA + abase + ((0 + dy) * HS + dx) * PITCH);
            short8v ah1 = *(const short8v*)(ldsA + abase + ((2 + dy) * HS + dx) * PITCH);
            acc[0][0] = __builtin_amdgcn_mfma_f32_16x16x32_bf16(ah0, bc0, acc[0][0], 0, 0, 0);
            acc[1][0] = __builtin_amdgcn_mfma_f32_16x16x32_bf16(ah1, bc0, acc[1][0], 0, 0, 0);
            acc[0][1] = __builtin_amdgcn_mfma_f32_16x16x32_bf16(ah0, bc1, acc[0][1], 0, 0, 0);
            acc[1][1] = __builtin_amdgcn_mfma_f32_16x16x32_bf16(ah1, bc1, acc[1][1], 0, 0, 0);
            if (dd < 8) { bc0 = bn0; bc1 = bn1; }
        }
    }
#undef AISSUE

    // ---- epilogue: transpose D frags via LDS, apply gates ----
    __syncthreads();
    float* lds2 = (float*)smem + w * 276;    // 16x17 pad, per-wave scratch
    const int rr = lane & 15, cl = lane >> 4;
#pragma unroll
    for (int nn = 0; nn < 2; ++nn) {
        const int ngl = ngb + nn;
        const int c = nb * 16 + ngl * 4 + cl;           // channel in [0,C)
        float b4[4];
#pragma unroll
        for (int g = 0; g < 4; ++g) b4[g] = bias[g * C + c];
#pragma unroll
        for (int fm = 0; fm < 2; ++fm) {
            // D layout: lane holds col=lane&15, rows (lane>>4)*4+j
#pragma unroll
            for (int j = 0; j < 4; ++j) lds2[(cl * 4 + j) * 17 + rr] = acc[fm][nn][j];
            float z[4];
#pragma unroll
            for (int g = 0; g < 4; ++g) z[g] = lds2[rr * 17 + cl * 4 + g];
            const int py = y0 + (w >> 1) * 4 + 2 * fm + (rr >> 3);
            const int px = x0 + (rr & 7);
            const size_t base = ((size_t)py * W + px) * C + c;
            const float cold = hprev ? cst[base] : 0.f;
            const float zi = z[0] + b4[0], zf = z[1] + b4[1];
            const float zc = z[2] + b4[2], zo = z[3] + b4[3];
            const float cn = hsig(zf) * cold + hsig(zi) * fmaxf(zc, 0.f);
            const float hv = hsig(zo) * fmaxf(cn, 0.f);
            cst[base] = cn; hout[base] = hv;
        }
    }
}

// ===== weight pre-transform: fp32 [3][3][Cs][4C] -> fragment-ordered bf16 =====
// layout: [ck][dd][ngrp][lane 0..63][8], k = ck*32+(lane>>4)*8+e,
// co' = ngrp*16 + (lane&15) = c*4+g  ->  src co = g*C + c.  ci>=CsR zero-filled.
struct TJob { const float* src; unsigned short* dst; int CsR; int C; int total; };
struct TJobs { TJob j[28]; };

__global__ void transform_all_kernel(TJobs jobs)
{
    const TJob J = jobs.j[blockIdx.y];
    const int i = blockIdx.x * 256 + threadIdx.x;
    if (i >= J.total) return;
    const int N = 4 * J.C, NG = N >> 4;
    const int lane = i & 63; int t = i >> 6;
    const int ng = t % NG; t /= NG;
    const int dd = t % 9; const int ck = t / 9;
    const int colp = ng * 16 + (lane & 15);
    const int c = colp >> 2, g = colp & 3, co = g * J.C + c;
    const int kb = (lane >> 4) * 8;
    short8v hi8;
#pragma unroll
    for (int e = 0; e < 8; ++e) {
        const int ci = (ck << 5) + kb + e;
        const float v = (ci < J.CsR) ? J.src[(size_t)(dd * J.CsR + ci) * N + co] : 0.f;
        hi8[e] = (short)f2bf(v);
    }
    const size_t base = ((size_t)(ck * 9 + dd) * NG + ng) * 512 + lane * 8;
    *(short8v*)(J.dst + base) = hi8;
}

// ---------------- MaxPool (1,2,2), NHWC, float4 over channels ----------------
__global__ void pool_kernel(const float* __restrict__ in, float* __restrict__ out,
                            int H, int Wd, int C, long total4)
{
    const int Ho = H >> 1, Wo = Wd >> 1;
    const int C4 = C >> 2;
    for (long i = (long)blockIdx.x * blockDim.x + threadIdx.x; i < total4;
         i += (long)gridDim.x * blockDim.x) {
        const int c4 = (int)(i % C4);
        long r = i / C4;
        const int x = (int)(r % Wo); r /= Wo;
        const int y = (int)(r % Ho);
        const int t = (int)(r / Ho);
        const float4* a = reinterpret_cast<const float4*>(in) +
                          (((long)t * H + 2 * y) * Wd + 2 * x) * C4 + c4;
        const float4 v00 = a[0], v01 = a[C4];
        const float4 v10 = a[(long)Wd * C4], v11 = a[(long)Wd * C4 + C4];
        float4 o;
        o.x = fmaxf(fmaxf(v00.x, v01.x), fmaxf(v10.x, v11.x));
        o.y = fmaxf(fmaxf(v00.y, v01.y), fmaxf(v10.y, v11.y));
        o.z = fmaxf(fmaxf(v00.z, v01.z), fmaxf(v10.z, v11.z));
        o.w = fmaxf(fmaxf(v00.w, v01.w), fmaxf(v10.w, v11.w));
        reinterpret_cast<float4*>(out)[i] = o;
    }
}

// ------------- concat([A, up2x2(B)], channel-last), float4 -------------
__global__ void upconcat_kernel(const float* __restrict__ A, const float* __restrict__ B,
                                float* __restrict__ out, int H, int Wd, int C1, int C2,
                                long total4)
{
    const int Co4 = (C1 + C2) >> 2, C14 = C1 >> 2, C24 = C2 >> 2;
    for (long i = (long)blockIdx.x * blockDim.x + threadIdx.x; i < total4;
         i += (long)gridDim.x * blockDim.x) {
        const int c4 = (int)(i % Co4);
        long r = i / Co4;
        const int x = (int)(r % Wd); r /= Wd;
        const int y = (int)(r % H);
        const int t = (int)(r / H);
        float4 v;
        if (c4 < C14)
            v = reinterpret_cast<const float4*>(A)[(((long)t * H + y) * Wd + x) * C14 + c4];
        else
            v = reinterpret_cast<const float4*>(B)[
                (((long)t * (H >> 1) + (y >> 1)) * (Wd >> 1) + (x >> 1)) * C24 + (c4 - C14)];
        reinterpret_cast<float4*>(out)[i] = v;
    }
}

// ------------- final 1x1 ConvLSTM, Cin=32 -> C=1 -------------
__global__ void final_step_kernel(const float* __restrict__ h7, const float* __restrict__ hprev,
                                  float* __restrict__ cst, float* __restrict__ hout,
                                  const float* __restrict__ wout,  // [32][4]
                                  const float* __restrict__ uout,  // [4]
                                  const float* __restrict__ bout,  // [4]
                                  float* __restrict__ dout, int N)
{
    const int i = blockIdx.x * 256 + threadIdx.x;
    if (i >= N) return;
    float z0 = bout[0], z1 = bout[1], z2 = bout[2], z3 = bout[3];
    const float* hp = h7 + (size_t)i * 32;
#pragma unroll
    for (int c = 0; c < 32; c += 4) {
        const float4 h4 = *reinterpret_cast<const float4*>(hp + c);
        const float hv4[4] = {h4.x, h4.y, h4.z, h4.w};
#pragma unroll
        for (int j = 0; j < 4; ++j) {
            z0 += hv4[j] * wout[(c + j) * 4 + 0];
            z1 += hv4[j] * wout[(c + j) * 4 + 1];
            z2 += hv4[j] * wout[(c + j) * 4 + 2];
            z3 += hv4[j] * wout[(c + j) * 4 + 3];
        }
    }
    float hpv = 0.f, cold = 0.f;
    if (hprev) { hpv = hprev[i]; cold = cst[i]; }
    z0 += hpv * uout[0]; z1 += hpv * uout[1]; z2 += hpv * uout[2]; z3 += hpv * uout[3];
    const float ig = hsig(z0), fg = hsig(z1), og = hsig(z3);
    const float cd = fmaxf(z2, 0.f);
    const float cn = fg * cold + ig * cd;
    const float hv = og * fmaxf(cn, 0.f);
    cst[i] = cn; hout[i] = hv;
    if (dout) dout[i] = hv;
}

// ---------------- host orchestration ----------------
struct LD { int H, W, CiR, CiP, C, wi; };

static void run_layer(const LD& L, const float* in, float* out, float* cstate,
                      const unsigned short* btx, const unsigned short* bth,
                      const float* bias, hipStream_t stream)
{
    const size_t inS = (size_t)L.H * L.W * L.CiR, outS = (size_t)L.H * L.W * L.C;
    const dim3 grid(L.W / 8, L.H / 8, (4 * L.C) / 64);
    const size_t sh = 10 * 10 * 40 * 2;   // 8000 B
    for (int t = 0; t < T_STEPS; ++t) {
        const float* hp = t ? out + (t - 1) * outS : nullptr;
        lstm_mfma<<<grid, 256, sh, stream>>>(in + t * inS, hp, cstate, out + t * outS,
                                             btx, bth, bias, L.H, L.W, L.CiR, L.CiP, L.C);
    }
}

extern "C" void kernel_launch(void* const* d_in, const int* in_sizes, int n_in,
                              void* d_out, int out_size, void* d_ws, size_t ws_size,
                              hipStream_t stream)
{
    (void)in_sizes; (void)n_in; (void)out_size; (void)ws_size;
    const float* x = (const float*)d_in[0];
    auto Wp = [&](int k) { return (const float*)d_in[k]; };
    char* ws = (char*)d_ws;
    const size_t MiB = 1ull << 20;
    auto f = [&](size_t m) { return (float*)(ws + m * MiB); };

    hipFuncSetAttribute((const void*)lstm_mfma,
                        hipFuncAttributeMaxDynamicSharedMemorySize, 8192);

    // Arena (peak ~210 MiB; lifetimes hand-checked):
    float* bC1  = f(0);    float* bC2  = f(32);  float* bC3  = f(48);
    float* bCST = f(56);   // shared c-state, <= 8 MiB
    float* bHF  = (float*)(ws + 64 * MiB);
    float* bCF  = (float*)(ws + 64 * MiB + 256 * 1024);
    float* bS1A = f(65);   float* bP1  = f(97);  float* bS2A = f(105);
    float* bP2  = f(97);   float* bS3A = f(101); float* bP3  = f(65);
    float* bS4A = f(67);   float* bC4  = f(71);  float* bM5  = f(75);
    float* bS5A = f(99);   float* bC5  = f(65);  float* bM6  = f(73);
    float* bS6A = f(121);  float* bC6  = f(65);  float* bM7  = f(81);
    float* bS7A = f(0);    float* bC7  = f(81);

    static const LD Ls[14] = {
        {256, 256,   1,  32,  32,  1}, {256, 256,  32,  32,  32,  4},
        {128, 128,  32,  32,  64,  7}, {128, 128,  64,  64,  64, 10},
        { 64,  64,  64,  64, 128, 13}, { 64,  64, 128, 128, 128, 16},
        { 32,  32, 128, 128, 256, 19}, { 32,  32, 256, 256, 256, 22},
        { 64,  64, 384, 384, 128, 25}, { 64,  64, 128, 128, 128, 28},
        {128, 128, 192, 192,  64, 31}, {128, 128,  64,  64,  64, 34},
        {256, 256,  96,  96,  32, 37}, {256, 256,  32,  32,  32, 40},
    };

    // ---- weight transforms into Bt arena at [177 MiB, ...), ONE launch ----
    unsigned short* btx[14]; unsigned short* bth[14];
    {
        TJobs jobs;
        int maxTotal = 0;
        size_t cur = 177 * MiB;
        for (int i = 0; i < 14; ++i) {
            const LD& L = Ls[i];
            const int NG = (4 * L.C) >> 4;
            const size_t szx = (size_t)(L.CiP >> 5) * 9 * NG * 1024;  // bytes
            const size_t szh = (size_t)(L.C  >> 5) * 9 * NG * 1024;
            btx[i] = (unsigned short*)(ws + cur); cur += szx;
            bth[i] = (unsigned short*)(ws + cur); cur += szh;
            const int totx = (L.CiP >> 5) * 9 * NG * 64;
            const int toth = (L.C  >> 5) * 9 * NG * 64;
            jobs.j[2 * i]     = {Wp(L.wi),     btx[i], L.CiR, L.C, totx};
            jobs.j[2 * i + 1] = {Wp(L.wi + 1), bth[i], L.C,   L.C, toth};
            if (totx > maxTotal) maxTotal = totx;
            if (toth > maxTotal) maxTotal = toth;
        }
        transform_all_kernel<<<dim3((maxTotal + 255) / 256, 28), 256, 0, stream>>>(jobs);
    }

    auto pool = [&](const float* in, float* out, int H, int Wd, int C) {
        long total4 = (long)T_STEPS * (H / 2) * (Wd / 2) * (C / 4);
        long nb = (total4 + 255) / 256; if (nb > 4096) nb = 4096;
        pool_kernel<<<dim3((unsigned)nb), 256, 0, stream>>>(in, out, H, Wd, C, total4);
    };
    auto upcat = [&](const float* A, const float* B, float* out, int H, int Wd, int C1, int C2) {
        long total4 = (long)T_STEPS * H * Wd * ((C1 + C2) / 4);
        long nb = (total4 + 255) / 256; if (nb > 8192) nb = 8192;
        upconcat_kernel<<<dim3((unsigned)nb), 256, 0, stream>>>(A, B, out, H, Wd, C1, C2, total4);
    };
    auto run = [&](int i, const float* in, float* out) {
        run_layer(Ls[i], in, out, bCST, btx[i], bth[i], Wp(Ls[i].wi + 2), stream);
    };

    run(0, x, bS1A);        run(1, bS1A, bC1);
    pool(bC1, bP1, 256, 256, 32);
    run(2, bP1, bS2A);      run(3, bS2A, bC2);
    pool(bC2, bP2, 128, 128, 64);
    run(4, bP2, bS3A);      run(5, bS3A, bC3);
    pool(bC3, bP3, 64, 64, 128);
    run(6, bP3, bS4A);      run(7, bS4A, bC4);
    upcat(bC3, bC4, bM5, 64, 64, 128, 256);
    run(8, bM5, bS5A);      run(9, bS5A, bC5);
    upcat(bC2, bC5, bM6, 128, 128, 64, 128);
    run(10, bM6, bS6A);     run(11, bS6A, bC6);
    upcat(bC1, bC6, bM7, 256, 256, 32, 64);
    run(12, bM7, bS7A);     run(13, bS7A, bC7);

    const int N = 256 * 256;
    for (int t = 0; t < T_STEPS; ++t) {
        const float* h7 = bC7 + (size_t)t * N * 32;
        final_step_kernel<<<N / 256, 256, 0, stream>>>(
            h7, t ? bHF : nullptr, bCF, bHF, Wp(43), Wp(44), Wp(45),
            (t == T_STEPS - 1) ? (float*)d_out : nullptr, N);
    }
}